// Round 2
// baseline (144.788 us; speedup 1.0000x reference)
//
#include <hip/hip_runtime.h>
#include <hip/hip_bf16.h>

#define D 128
#define RBASE 40
#define NREL 80
#define TILE 32

// ---------------------------------------------------------------------------
// Workspace layout (int32 offsets from base of d_ws):
//   [0]              hist_rel[80]
//   [96]             off_rel[81]
//   [192]            cur_rel[80]
//   [512]            hist_dst[nn]
//   [512+nn]         off_dst[nn+1]
//   [512+2nn+8]      cur_dst[nn]
//   [512+3nn+8]      srcnode[2*ne]   (rel-sorted: virtual-edge source node)
//   [.. +2ne]        dslot[2*ne]     (rel-sorted: slot in dst-sorted msg buf)
//   [align16]        msg[2*ne * 128] float
// ---------------------------------------------------------------------------

__global__ void hist_kernel(const int* __restrict__ src,
                            const int* __restrict__ dst,
                            const int* __restrict__ rel,
                            int* __restrict__ hist_rel,
                            int* __restrict__ hist_dst,
                            int ne) {
    const int etot = 2 * ne;
    for (int e = blockIdx.x * blockDim.x + threadIdx.x; e < etot;
         e += gridDim.x * blockDim.x) {
        int r, d;
        if (e < ne) { r = rel[e];            d = dst[e];      }
        else        { r = rel[e - ne] + RBASE; d = src[e - ne]; }
        atomicAdd(hist_rel + r, 1);
        atomicAdd(hist_dst + d, 1);
    }
}

// single block, 1024 threads: exclusive scans for rel (80) and dst (nn<=8192)
__global__ void scan_kernel(const int* __restrict__ hist_rel,
                            int* __restrict__ off_rel,
                            int* __restrict__ cur_rel,
                            const int* __restrict__ hist_dst,
                            int* __restrict__ off_dst,
                            int* __restrict__ cur_dst,
                            int nn) {
    __shared__ int part[1024];
    const int t = threadIdx.x;
    const int CH = (nn + 1023) / 1024;   // 8 for nn=8192
    int loc[8];
    int s = 0;
    #pragma unroll
    for (int i = 0; i < 8; ++i) {
        int idx = t * CH + i;
        int v = (i < CH && idx < nn) ? hist_dst[idx] : 0;
        loc[i] = v;
        s += v;
    }
    part[t] = s;
    __syncthreads();
    for (int st = 1; st < 1024; st <<= 1) {
        int v = (t >= st) ? part[t - st] : 0;
        __syncthreads();
        part[t] += v;
        __syncthreads();
    }
    int run = part[t] - s;   // exclusive prefix of this thread's chunk
    #pragma unroll
    for (int i = 0; i < 8; ++i) {
        int idx = t * CH + i;
        if (i < CH && idx < nn) {
            off_dst[idx] = run;
            cur_dst[idx] = run;
            run += loc[i];
        }
    }
    if (t == 1023) off_dst[nn] = part[1023];
    if (t == 0) {
        int acc = 0;
        for (int i = 0; i < NREL; ++i) {
            off_rel[i] = acc;
            cur_rel[i] = acc;
            acc += hist_rel[i];
        }
        off_rel[NREL] = acc;
    }
}

__global__ void scatter_kernel(const int* __restrict__ src,
                               const int* __restrict__ dst,
                               const int* __restrict__ rel,
                               int* __restrict__ cur_rel,
                               int* __restrict__ cur_dst,
                               int* __restrict__ srcnode,
                               int* __restrict__ dslot,
                               int ne) {
    const int etot = 2 * ne;
    for (int e = blockIdx.x * blockDim.x + threadIdx.x; e < etot;
         e += gridDim.x * blockDim.x) {
        int r, d, sn;
        if (e < ne) { r = rel[e];              d = dst[e];       sn = src[e]; }
        else        { r = rel[e - ne] + RBASE; d = src[e - ne];  sn = dst[e - ne]; }
        int pr = atomicAdd(cur_rel + r, 1);
        int pd = atomicAdd(cur_dst + d, 1);
        srcnode[pr] = sn;
        dslot[pr]   = pd;
    }
}

// ---------------------------------------------------------------------------
// Self transform: out[i][j] = sum_k x[i][k] * W_self[j][k] + b_self[j]
// ---------------------------------------------------------------------------
__global__ void self_kernel(const float* __restrict__ x,
                            const float* __restrict__ Ws,
                            const float* __restrict__ bs,
                            float* __restrict__ out, int n) {
    __shared__ float vbuf[32][D];
    const int row0 = blockIdx.x * 32;
    const int tid  = threadIdx.x;

    for (int li = tid; li < 32 * (D / 4); li += 256) {
        int r = li >> 5;
        int c = li & 31;
        int row = row0 + r;
        float4 v = make_float4(0.f, 0.f, 0.f, 0.f);
        if (row < n)
            v = reinterpret_cast<const float4*>(x + (size_t)row * D)[c];
        reinterpret_cast<float4*>(vbuf[r])[c] = v;
    }
    __syncthreads();

    const int eg = tid >> 5;
    const int jg = tid & 31;

    float acc[4][4];
    #pragma unroll
    for (int b = 0; b < 4; ++b)
        #pragma unroll
        for (int a = 0; a < 4; ++a) acc[b][a] = 0.f;

    #pragma unroll 4
    for (int k = 0; k < D; k += 4) {
        float4 w[4], v[4];
        #pragma unroll
        for (int a = 0; a < 4; ++a)
            w[a] = *reinterpret_cast<const float4*>(Ws + (size_t)(jg * 4 + a) * D + k);
        #pragma unroll
        for (int b = 0; b < 4; ++b)
            v[b] = *reinterpret_cast<const float4*>(&vbuf[eg * 4 + b][k]);
        #pragma unroll
        for (int b = 0; b < 4; ++b)
            #pragma unroll
            for (int a = 0; a < 4; ++a)
                acc[b][a] += v[b].x * w[a].x + v[b].y * w[a].y +
                             v[b].z * w[a].z + v[b].w * w[a].w;
    }

    const float4 bias = *reinterpret_cast<const float4*>(bs + jg * 4);
    #pragma unroll
    for (int b = 0; b < 4; ++b) {
        int row = row0 + eg * 4 + b;
        if (row < n) {
            float4 res = make_float4(acc[b][0] + bias.x, acc[b][1] + bias.y,
                                     acc[b][2] + bias.z, acc[b][3] + bias.w);
            *reinterpret_cast<float4*>(out + (size_t)row * D + jg * 4) = res;
        }
    }
}

// ---------------------------------------------------------------------------
// Edge GEMM over the relation-sorted edge list. Each block: one relation,
// tiles of 32 edges (strided by gridDim.y). Message (W[r]@x[src] + b[r])
// written NON-atomically to its dst-sorted slot.
// ---------------------------------------------------------------------------
__global__ void edge_gemm(const float* __restrict__ x,
                          const float* __restrict__ Wr,
                          const float* __restrict__ br,
                          const int* __restrict__ off_rel,
                          const int* __restrict__ srcnode,
                          const int* __restrict__ dslot,
                          float* __restrict__ msg) {
    __shared__ float vbuf[TILE][D];
    __shared__ int   sE[TILE];
    __shared__ int   dS[TILE];

    const int r   = blockIdx.x;
    const int tid = threadIdx.x;
    const int s0  = off_rel[r];
    const int cnt = off_rel[r + 1] - s0;
    if (cnt == 0) return;

    const float* W  = Wr + (size_t)r * D * D;
    const int    jg = tid & 31;
    const int    eg = tid >> 5;
    const float4 bias = *reinterpret_cast<const float4*>(br + (size_t)r * D + jg * 4);

    for (int t0 = blockIdx.y * TILE; t0 < cnt; t0 += gridDim.y * TILE) {
        if (tid < TILE) {
            int s = -1, d = -1;
            if (t0 + tid < cnt) {
                s = srcnode[s0 + t0 + tid];
                d = dslot[s0 + t0 + tid];
            }
            sE[tid] = s;
            dS[tid] = d;
        }
        __syncthreads();

        for (int li = tid; li < TILE * (D / 4); li += 256) {
            int row = li >> 5;
            int c   = li & 31;
            int s   = sE[row];
            float4 v = make_float4(0.f, 0.f, 0.f, 0.f);
            if (s >= 0)
                v = reinterpret_cast<const float4*>(x + (size_t)s * D)[c];
            reinterpret_cast<float4*>(vbuf[row])[c] = v;
        }
        __syncthreads();

        float acc[4][4];
        #pragma unroll
        for (int b = 0; b < 4; ++b)
            #pragma unroll
            for (int a = 0; a < 4; ++a) acc[b][a] = 0.f;

        #pragma unroll 4
        for (int k = 0; k < D; k += 4) {
            float4 w[4], v[4];
            #pragma unroll
            for (int a = 0; a < 4; ++a)
                w[a] = *reinterpret_cast<const float4*>(W + (size_t)(jg * 4 + a) * D + k);
            #pragma unroll
            for (int b = 0; b < 4; ++b)
                v[b] = *reinterpret_cast<const float4*>(&vbuf[eg * 4 + b][k]);
            #pragma unroll
            for (int b = 0; b < 4; ++b)
                #pragma unroll
                for (int a = 0; a < 4; ++a)
                    acc[b][a] += v[b].x * w[a].x + v[b].y * w[a].y +
                                 v[b].z * w[a].z + v[b].w * w[a].w;
        }

        #pragma unroll
        for (int b = 0; b < 4; ++b) {
            int row = eg * 4 + b;
            int ds  = dS[row];
            if (ds >= 0) {
                float4 res = make_float4(acc[b][0] + bias.x, acc[b][1] + bias.y,
                                         acc[b][2] + bias.z, acc[b][3] + bias.w);
                *reinterpret_cast<float4*>(msg + (size_t)ds * D + jg * 4) = res;
            }
        }
        __syncthreads();
    }
}

// ---------------------------------------------------------------------------
// Gather: out[v] += sum of msg rows in [off_dst[v], off_dst[v+1])
// 32 threads per node row, 8 nodes per block.
// ---------------------------------------------------------------------------
__global__ void gather_kernel(const float* __restrict__ msg,
                              const int* __restrict__ off_dst,
                              float* __restrict__ out, int nn) {
    const int tid = threadIdx.x;
    const int v   = blockIdx.x * 8 + (tid >> 5);
    const int jg  = tid & 31;
    if (v >= nn) return;
    const int a = off_dst[v];
    const int b = off_dst[v + 1];
    float4 acc = make_float4(0.f, 0.f, 0.f, 0.f);
    for (int s = a; s < b; ++s) {
        float4 m = *reinterpret_cast<const float4*>(msg + (size_t)s * D + jg * 4);
        acc.x += m.x; acc.y += m.y; acc.z += m.z; acc.w += m.w;
    }
    float* o = out + (size_t)v * D + jg * 4;
    float4 cur = *reinterpret_cast<float4*>(o);
    cur.x += acc.x; cur.y += acc.y; cur.z += acc.z; cur.w += acc.w;
    *reinterpret_cast<float4*>(o) = cur;
}

extern "C" void kernel_launch(void* const* d_in, const int* in_sizes, int n_in,
                              void* d_out, int out_size, void* d_ws, size_t ws_size,
                              hipStream_t stream) {
    const float* x   = (const float*)d_in[0];
    const float* Ws  = (const float*)d_in[1];
    const float* bs  = (const float*)d_in[2];
    const float* Wr  = (const float*)d_in[3];
    const float* br  = (const float*)d_in[4];
    const int*   src = (const int*)d_in[5];
    const int*   dst = (const int*)d_in[6];
    const int*   rel = (const int*)d_in[7];
    float*       out = (float*)d_out;

    const int ne = in_sizes[5];          // edges
    const int nn = in_sizes[0] / D;      // nodes
    if (ne <= 0 || nn <= 0) return;

    int* IW = (int*)d_ws;
    int* hist_rel = IW + 0;
    int* off_rel  = IW + 96;
    int* cur_rel  = IW + 192;
    int* hist_dst = IW + 512;
    int* off_dst  = hist_dst + nn;
    int* cur_dst  = off_dst + nn + 8;
    int* srcn     = cur_dst + nn;
    int* dslot    = srcn + 2 * ne;
    int  msg_off  = (int)((dslot + 2 * ne) - IW);
    msg_off = (msg_off + 3) & ~3;        // 16B align
    float* msg = (float*)(IW + msg_off);

    // zero the histograms (covers hist_rel..hist_dst end)
    hipMemsetAsync(d_ws, 0, (size_t)(512 + nn) * sizeof(int), stream);

    hist_kernel<<<64, 256, 0, stream>>>(src, dst, rel, hist_rel, hist_dst, ne);
    scan_kernel<<<1, 1024, 0, stream>>>(hist_rel, off_rel, cur_rel,
                                        hist_dst, off_dst, cur_dst, nn);
    scatter_kernel<<<64, 256, 0, stream>>>(src, dst, rel, cur_rel, cur_dst,
                                           srcn, dslot, ne);

    self_kernel<<<(nn + 31) / 32, 256, 0, stream>>>(x, Ws, bs, out, nn);

    edge_gemm<<<dim3(NREL, 8), 256, 0, stream>>>(x, Wr, br, off_rel,
                                                 srcn, dslot, msg);

    gather_kernel<<<(nn + 7) / 8, 256, 0, stream>>>(msg, off_dst, out, nn);
}

// Round 3
// 61.782 us; speedup vs baseline: 2.3435x; 2.3435x over previous
//
#include <hip/hip_runtime.h>
#include <hip/hip_bf16.h>

#define D 128
#define RBASE 40
#define NREL 80
#define NR1 81          // 80 relations + self pseudo-relation (index 80)
#define TILE 64         // edges per GEMM tile
#define PT 1024         // prep threads

typedef __attribute__((ext_vector_type(8))) short short8;
typedef __attribute__((ext_vector_type(4))) float f32x4;

static __device__ __forceinline__ unsigned short f2bf(float f) {
    unsigned int u = __float_as_uint(f);
    u += 0x7FFF + ((u >> 16) & 1);          // RNE
    return (unsigned short)(u >> 16);
}
static __device__ __forceinline__ float bf2f(unsigned short h) {
    return __uint_as_float(((unsigned int)h) << 16);
}

// ---------------------------------------------------------------------------
// Convert W_rel (80xDxD) and W_self (DxD) into one bf16 array Wbf[81][D][D].
// ---------------------------------------------------------------------------
__global__ void convert_w(const float* __restrict__ Wr,
                          const float* __restrict__ Ws,
                          unsigned short* __restrict__ Wbf) {
    const int total4 = NR1 * D * D / 4;
    for (int i = blockIdx.x * blockDim.x + threadIdx.x; i < total4;
         i += gridDim.x * blockDim.x) {
        int e0 = i * 4;
        const float* sp = (e0 < NREL * D * D) ? (Wr + e0) : (Ws + (e0 - NREL * D * D));
        float4 v = *reinterpret_cast<const float4*>(sp);
        ushort4 o;
        o.x = f2bf(v.x); o.y = f2bf(v.y); o.z = f2bf(v.z); o.w = f2bf(v.w);
        *reinterpret_cast<ushort4*>(Wbf + e0) = o;
    }
}

// ---------------------------------------------------------------------------
// Fused preprocessing, ONE block (1024 threads), everything in LDS:
//  - histogram virtual edges by relation (81 bins; self rel = nn analytically)
//  - histogram by dst node (nn bins; +1 self per node)
//  - exclusive scans (wave shfl scans)
//  - scatter: rel-sorted edge list (srcnode, dslot) + dst-sorted slot assign
//  - balanced tile list: one entry per 64-edge tile of each relation
// Requires nn <= 8192.
// ---------------------------------------------------------------------------
__global__ __launch_bounds__(PT) void prep_kernel(
        const int* __restrict__ src, const int* __restrict__ dst,
        const int* __restrict__ rel,
        int* __restrict__ srcnode, int* __restrict__ dslot,
        int* __restrict__ off_dst_g,
        int* __restrict__ tile_rel, int* __restrict__ tile_start,
        int* __restrict__ tile_mr,
        int ne, int nn, int nt_max) {
    __shared__ int h_rel[NR1];
    __shared__ int off_rel_s[NR1];
    __shared__ int cur_rel_s[NR1];
    __shared__ int toff_s[NR1 + 1];
    __shared__ int cnt_dst[8192];      // hist -> cur counter
    __shared__ int woff[16];

    const int t    = threadIdx.x;
    const int lane = t & 63;
    const int wid  = t >> 6;
    const int etot = 2 * ne;

    for (int i = t; i < nn; i += PT) cnt_dst[i] = 0;
    if (t < NR1) h_rel[t] = (t == NREL) ? nn : 0;   // self rel count known
    __syncthreads();

    // pass 1: histograms (real edges only)
    for (int e = t; e < etot; e += PT) {
        int r, d;
        if (e < ne) { r = rel[e];              d = dst[e];      }
        else        { r = rel[e - ne] + RBASE; d = src[e - ne]; }
        atomicAdd(&h_rel[r], 1);
        atomicAdd(&cnt_dst[d], 1);
    }
    __syncthreads();

    // relation scan + tile-count scan (wave 0, 2 bins per lane)
    if (wid == 0) {
        int i0 = 2 * lane, i1 = 2 * lane + 1;
        int b0 = (i0 < NR1) ? h_rel[i0] : 0;
        int b1 = (i1 < NR1) ? h_rel[i1] : 0;
        int s = b0 + b1;
        int inc = s;
        for (int dd = 1; dd < 64; dd <<= 1) {
            int v = __shfl_up(inc, dd);
            if (lane >= dd) inc += v;
        }
        int exc = inc - s;
        if (i0 < NR1) { off_rel_s[i0] = exc;      cur_rel_s[i0] = exc;      }
        if (i1 < NR1) { off_rel_s[i1] = exc + b0; cur_rel_s[i1] = exc + b0; }
        int t0c = (i0 < NR1) ? ((b0 + TILE - 1) >> 6) : 0;
        int t1c = (i1 < NR1) ? ((b1 + TILE - 1) >> 6) : 0;
        int ts = t0c + t1c;
        int tinc = ts;
        for (int dd = 1; dd < 64; dd <<= 1) {
            int v = __shfl_up(tinc, dd);
            if (lane >= dd) tinc += v;
        }
        int texc = tinc - ts;
        if (i0 < NR1) toff_s[i0] = texc;
        if (i1 < NR1) toff_s[i1] = texc + t0c;
        if (lane == 63) toff_s[NR1] = tinc;       // ntiles
    }
    __syncthreads();

    // dst scan (+1 self per node); write off_dst, init cur, emit self entries
    const int CH = (nn + PT - 1) / PT;            // 8 for nn=8192
    int segs[8];
    int ssum = 0;
    const int base = t * CH;
    for (int i = 0; i < 8; ++i) {
        int idx = base + i;
        int v = (i < CH && idx < nn) ? (cnt_dst[idx] + 1) : 0;
        segs[i] = v;
        ssum += v;
    }
    int inc = ssum;
    for (int dd = 1; dd < 64; dd <<= 1) {
        int v = __shfl_up(inc, dd);
        if (lane >= dd) inc += v;
    }
    if (lane == 63) woff[wid] = inc;
    __syncthreads();
    if (t < 16) {
        int v = woff[t];
        int wi = v;
        for (int dd = 1; dd < 16; dd <<= 1) {
            int u = __shfl_up(wi, dd);
            if (lane >= dd) wi += u;
        }
        woff[t] = wi - v;                          // exclusive
    }
    __syncthreads();
    int off = woff[wid] + (inc - ssum);
    const int selfbase = off_rel_s[NREL];
    for (int i = 0; i < 8; ++i) {
        int idx = base + i;
        if (i < CH && idx < nn) {
            off_dst_g[idx] = off;
            srcnode[selfbase + idx] = idx;         // self edge: src = node
            dslot[selfbase + idx]   = off;         // self takes first slot
            cnt_dst[idx] = off + 1;                // real edges start after
            off += segs[i];
        }
    }
    if (t == PT - 1) off_dst_g[nn] = off;          // last thread owns tail bins
    __syncthreads();

    // pass 2: scatter real edges
    for (int e = t; e < etot; e += PT) {
        int r, d, sn;
        if (e < ne) { r = rel[e];              d = dst[e];      sn = src[e];      }
        else        { r = rel[e - ne] + RBASE; d = src[e - ne]; sn = dst[e - ne]; }
        int pr = atomicAdd(&cur_rel_s[r], 1);
        int pd = atomicAdd(&cnt_dst[d], 1);
        srcnode[pr] = sn;
        dslot[pr]   = pd;
    }

    // tile list
    if (t < NR1) {
        int cnt = h_rel[t];
        int ntr = (cnt + TILE - 1) >> 6;
        int tb  = toff_s[t];
        int s0  = off_rel_s[t];
        for (int i = 0; i < ntr; ++i) {
            tile_rel[tb + i]   = t;
            tile_start[tb + i] = s0 + i * TILE;
            tile_mr[tb + i]    = min(TILE, cnt - i * TILE);
        }
    }
    const int ntiles = toff_s[NR1];
    for (int i = ntiles + t; i < nt_max; i += PT) tile_mr[i] = 0;
}

// ---------------------------------------------------------------------------
// MFMA edge GEMM. One 64-edge tile per block, 256 threads (4 waves).
// C[j][e] = sum_k W[j][k] * x[e][k]  (A = W rows, B = x^T), so each lane's
// 4 acc regs are 4 CONSECUTIVE output cols j -> packed 8B bf16 msg stores.
// LDS tiles XOR-swizzled (chunk ^= row&7) to kill ds_read_b128 bank conflicts.
// ---------------------------------------------------------------------------
__global__ __launch_bounds__(256) void edge_mfma(
        const float* __restrict__ x,
        const unsigned short* __restrict__ Wbf,
        const float* __restrict__ br, const float* __restrict__ bs,
        const int* __restrict__ srcnode, const int* __restrict__ dslot,
        const int* __restrict__ tile_rel, const int* __restrict__ tile_start,
        const int* __restrict__ tile_mr,
        unsigned short* __restrict__ msg) {
    __shared__ short Wl[D * D];        // 32 KB bf16, swizzled
    __shared__ short Xl[TILE * D];     // 16 KB bf16, swizzled
    __shared__ int   sEn[TILE];
    __shared__ int   dS[TILE];

    const int bid = blockIdx.x;
    const int mr  = tile_mr[bid];
    if (mr == 0) return;
    const int r   = tile_rel[bid];
    const int s0  = tile_start[bid];
    const int tid  = threadIdx.x;
    const int lane = tid & 63;
    const int wid  = tid >> 6;

    if (tid < TILE) {
        bool ok = tid < mr;
        sEn[tid] = ok ? srcnode[s0 + tid] : -1;
        dS[tid]  = ok ? dslot[s0 + tid]   : -1;
    }

    // stage W (2048 16B chunks): read global at swizzle-inverse, write linear
    const unsigned short* Wr = Wbf + (size_t)r * D * D;
    #pragma unroll
    for (int j = 0; j < 8; ++j) {
        int c   = tid + j * 256;       // physical chunk
        int row = c >> 4;
        int sc  = (c & 15) ^ (row & 7);
        uint4 v = *reinterpret_cast<const uint4*>(Wr + row * D + sc * 8);
        *reinterpret_cast<uint4*>(&Wl[c * 8]) = v;
    }
    __syncthreads();                   // sEn ready

    // stage X (1024 chunks), f32 -> bf16 during staging
    #pragma unroll
    for (int j = 0; j < 4; ++j) {
        int c    = tid + j * 256;
        int row  = c >> 4;             // edge row
        int sc   = (c & 15) ^ (row & 7);
        int node = sEn[row];
        short8 o = {0, 0, 0, 0, 0, 0, 0, 0};
        if (node >= 0) {
            const float* xp = x + (size_t)node * D + sc * 8;
            float4 a = *reinterpret_cast<const float4*>(xp);
            float4 b = *reinterpret_cast<const float4*>(xp + 4);
            o[0] = (short)f2bf(a.x); o[1] = (short)f2bf(a.y);
            o[2] = (short)f2bf(a.z); o[3] = (short)f2bf(a.w);
            o[4] = (short)f2bf(b.x); o[5] = (short)f2bf(b.y);
            o[6] = (short)f2bf(b.z); o[7] = (short)f2bf(b.w);
        }
        *reinterpret_cast<short8*>(&Xl[c * 8]) = o;
    }
    __syncthreads();

    const int q   = lane >> 4;         // 0..3
    const int l15 = lane & 15;

    f32x4 acc[2][4];
    #pragma unroll
    for (int mf = 0; mf < 2; ++mf)
        #pragma unroll
        for (int nf = 0; nf < 4; ++nf)
            acc[mf][nf] = (f32x4){0.f, 0.f, 0.f, 0.f};

    #pragma unroll
    for (int ks = 0; ks < 4; ++ks) {
        short8 a[2], b[4];
        #pragma unroll
        for (int mf = 0; mf < 2; ++mf) {
            int row = (wid * 2 + mf) * 16 + l15;
            int pc  = (ks * 4 + q) ^ (row & 7);
            a[mf] = *reinterpret_cast<const short8*>(&Wl[row * D + pc * 8]);
        }
        #pragma unroll
        for (int nf = 0; nf < 4; ++nf) {
            int er = nf * 16 + l15;
            int pc = (ks * 4 + q) ^ (er & 7);
            b[nf] = *reinterpret_cast<const short8*>(&Xl[er * D + pc * 8]);
        }
        #pragma unroll
        for (int mf = 0; mf < 2; ++mf)
            #pragma unroll
            for (int nf = 0; nf < 4; ++nf)
                acc[mf][nf] = __builtin_amdgcn_mfma_f32_16x16x32_bf16(
                    a[mf], b[nf], acc[mf][nf], 0, 0, 0);
    }

    // epilogue: +bias, pack 4 bf16 (4 consecutive j), 8B store per frag
    const float* bp = (r == NREL) ? bs : (br + (size_t)r * D);
    #pragma unroll
    for (int mf = 0; mf < 2; ++mf) {
        int j0 = (wid * 2 + mf) * 16 + q * 4;
        float4 bias = *reinterpret_cast<const float4*>(bp + j0);
        #pragma unroll
        for (int nf = 0; nf < 4; ++nf) {
            int e  = nf * 16 + l15;
            int ds = dS[e];
            if (ds >= 0) {
                f32x4 v = acc[mf][nf];
                unsigned int lo = (unsigned int)f2bf(v[0] + bias.x) |
                                  ((unsigned int)f2bf(v[1] + bias.y) << 16);
                unsigned int hi = (unsigned int)f2bf(v[2] + bias.z) |
                                  ((unsigned int)f2bf(v[3] + bias.w) << 16);
                *reinterpret_cast<uint2*>(msg + (size_t)ds * D + j0) =
                    make_uint2(lo, hi);
            }
        }
    }
}

// ---------------------------------------------------------------------------
// Gather: out[v] = f32 sum of bf16 msg rows [off_dst[v], off_dst[v+1]).
// 32 threads per node (4 cols each), 8 nodes per block.
// ---------------------------------------------------------------------------
__global__ void gather_kernel(const unsigned short* __restrict__ msg,
                              const int* __restrict__ off_dst,
                              float* __restrict__ out, int nn) {
    const int tid = threadIdx.x;
    const int v   = blockIdx.x * 8 + (tid >> 5);
    const int j   = tid & 31;
    if (v >= nn) return;
    const int a = off_dst[v];
    const int b = off_dst[v + 1];
    float a0 = 0.f, a1 = 0.f, a2 = 0.f, a3 = 0.f;
    for (int s = a; s < b; ++s) {
        ushort4 m = *reinterpret_cast<const ushort4*>(msg + (size_t)s * D + j * 4);
        a0 += bf2f(m.x); a1 += bf2f(m.y); a2 += bf2f(m.z); a3 += bf2f(m.w);
    }
    *reinterpret_cast<float4*>(out + (size_t)v * D + j * 4) =
        make_float4(a0, a1, a2, a3);
}

extern "C" void kernel_launch(void* const* d_in, const int* in_sizes, int n_in,
                              void* d_out, int out_size, void* d_ws, size_t ws_size,
                              hipStream_t stream) {
    const float* x   = (const float*)d_in[0];
    const float* Ws  = (const float*)d_in[1];
    const float* bs  = (const float*)d_in[2];
    const float* Wr  = (const float*)d_in[3];
    const float* br  = (const float*)d_in[4];
    const int*   src = (const int*)d_in[5];
    const int*   dst = (const int*)d_in[6];
    const int*   rel = (const int*)d_in[7];
    float*       out = (float*)d_out;

    const int ne = in_sizes[5];
    const int nn = in_sizes[0] / D;
    if (ne <= 0 || nn <= 0) return;

    const int tot    = 2 * ne + nn;                       // virtual + self edges
    const int nt_max = (2 * ne + 63) / 64 + NREL + (nn + 63) / 64;

    // workspace layout
    char* W0 = (char*)d_ws;
    int* off_dst = (int*)W0;                              // nn+1
    int* srcn    = off_dst + (nn + 1);                    // tot
    int* dslt    = srcn + tot;                            // tot
    int* t_rel   = dslt + tot;                            // nt_max
    int* t_start = t_rel + nt_max;                        // nt_max
    int* t_mr    = t_start + nt_max;                      // nt_max
    size_t ofs = (size_t)((char*)(t_mr + nt_max) - W0);
    ofs = (ofs + 15) & ~(size_t)15;
    unsigned short* Wbf = (unsigned short*)(W0 + ofs);    // NR1*D*D bf16
    ofs += (size_t)NR1 * D * D * 2;
    ofs = (ofs + 15) & ~(size_t)15;
    unsigned short* msg = (unsigned short*)(W0 + ofs);    // tot*D bf16

    convert_w<<<1024, 256, 0, stream>>>(Wr, Ws, Wbf);
    prep_kernel<<<1, PT, 0, stream>>>(src, dst, rel, srcn, dslt, off_dst,
                                      t_rel, t_start, t_mr, ne, nn, nt_max);
    edge_mfma<<<nt_max, 256, 0, stream>>>(x, Wbf, br, bs, srcn, dslt,
                                          t_rel, t_start, t_mr, msg);
    gather_kernel<<<(nn + 7) / 8, 256, 0, stream>>>(msg, off_dst, out, nn);
}